// Round 13
// baseline (173.523 us; speedup 1.0000x reference)
//
#include <hip/hip_runtime.h>
#include <hip/hip_fp16.h>
#include <math.h>

#define TPB 256

// Problem constants
constexpr int Bc = 16, Tc = 1536;
constexpr int T2c = 192;           // T / P1
constexpr float EPSc = 1e-5f;
constexpr float NSLOPE = 0.2f;
constexpr int MDI = 16;            // padded in-degree stride (bytes)
constexpr int MDO = 8;             // padded out-degree stride (bytes)

// Workspace layout (float offsets)
constexpr int OW_WEFF = 0;         // [32 k][32 f2]
constexpr int OW_CHL  = 1024;      // [32]
constexpr int OW_CES  = 1056;      // ces[4] | ced[4]
constexpr int OW_WES  = 1064;      // [4 h][32 k]   (h-major: wave-uniform s_load)
constexpr int OW_WED  = 1192;      // [4 h][32 k]
constexpr int OW_GRAPH= 1320;      // 417 ints packed byte graph
constexpr int OW_P    = 1740;      // [B][192][32]

// Packed graph byte offsets:
//   [0,1024)    in-lists  isrc[d*16+e]  (pad 0)
//   [1024,1088) indeg[d]  (clamped)
//   [1088,1600) out-lists outdst[v*8+j] (pad 0)
//   [1600,1664) outdeg[v] (clamped)
//   [1664] max in-degree   [1665] max out-degree
constexpr int GB_INTS = 417;

// gat LDS layout (float offsets)
constexpr int L_XT  = 0;           // xT [40 c][68 v]; row 39 = ones (S column)
constexpr int L_WB  = 2720;        // [4 h][8 t][68 v]
constexpr int L_Y   = 4896;        // [4 h][8 t][41]
constexpr int L_GR  = 6208;        // 417 ints packed graph
constexpr int L_TOT = 6625;        // 26.5 KB -> 6 blocks/CU
constexpr int L_G   = L_GR;        // [8 t][stride 36] aliases graph bytes.
                                   // SAFE: graph only read in phase B; block barrier
                                   // separates C from D's G writes.

static __device__ __forceinline__ int pack_h2(float a, float b) {
    __half2 h = __floats2half2_rn(a, b);
    return *(int*)&h;
}
static __device__ __forceinline__ float2 unpack_h2(int i) {
    __half2 h = *(__half2*)&i;
    return make_float2(__low2float(h), __high2float(h));
}

// ---------------------------------------------------------------------------
// Prep (1 block): fold bn1+gatW+conv1 -> weff/chl; es/ed conv weights in
// [h][k] layout (for wave-uniform scalar loads in gat); packed byte graph.
// ---------------------------------------------------------------------------
__global__ void prep_kernel(const float* __restrict__ c1w,
                            const float* __restrict__ g1, const float* __restrict__ b1,
                            const float* __restrict__ m1, const float* __restrict__ v1,
                            const float* __restrict__ W,
                            const float* __restrict__ asrc, const float* __restrict__ adst,
                            const int* __restrict__ ei, int ne, float* __restrict__ ws)
{
    const int tid = threadIdx.x;
    __shared__ float sweff[1024];
    __shared__ float schl[32];
    __shared__ int isrcp_i[64 * MDI];
    __shared__ int outdst_i[64 * MDO];
    __shared__ int inslot[64], outslot[64];

    // weff[k*32+f2] = sum_f a1[f]*W[f,f2]*w1[f,k]
    for (int idx = tid; idx < 1024; idx += TPB) {
        int k = idx >> 5, f2 = idx & 31;
        float s = 0.f;
        for (int f = 0; f < 16; f++) {
            float a1 = g1[f] * rsqrtf(v1[f] + EPSc);
            s += a1 * W[f * 32 + f2] * c1w[f * 32 + k];
        }
        ws[OW_WEFF + idx] = s;
        sweff[idx] = s;
    }
    for (int f2 = tid; f2 < 32; f2 += TPB) {
        float s = 0.f;
        for (int f = 0; f < 16; f++) {
            float a1 = g1[f] * rsqrtf(v1[f] + EPSc);
            s = fmaf(b1[f] - a1 * m1[f], W[f * 32 + f2], s);
        }
        ws[OW_CHL + f2] = s;
        schl[f2] = s;
    }

    // graph: padded in/out lists (LDS atomics)
    for (int i = tid; i < 64 * MDI; i += TPB) isrcp_i[i] = 0;
    for (int i = tid; i < 64 * MDO; i += TPB) outdst_i[i] = 0;
    if (tid < 64) { inslot[tid] = 0; outslot[tid] = 0; }
    __syncthreads();
    for (int e = tid; e < ne; e += TPB) {
        int s = ei[e], d = ei[ne + e];
        int pi = atomicAdd(&inslot[d], 1);
        if (pi < MDI) isrcp_i[d * MDI + pi] = s;
        int po = atomicAdd(&outslot[s], 1);
        if (po < MDO) outdst_i[s * MDO + po] = d;
    }
    __syncthreads();

    // wes/wed in [h][k] layout + ces/ced
    if (tid < 128) {
        int k = tid >> 2, h = tid & 3;
        float s1 = 0.f, s2 = 0.f;
        for (int o = 0; o < 8; o++) {
            float wv = sweff[k * 32 + h * 8 + o];
            s1 = fmaf(asrc[h * 8 + o], wv, s1);
            s2 = fmaf(adst[h * 8 + o], wv, s2);
        }
        ws[OW_WES + h * 32 + k] = s1;
        ws[OW_WED + h * 32 + k] = s2;
    }
    if (tid < 4) {
        float s1 = 0.f, s2 = 0.f;
        for (int o = 0; o < 8; o++) {
            float cv = schl[tid * 8 + o];
            s1 = fmaf(asrc[tid * 8 + o], cv, s1);
            s2 = fmaf(adst[tid * 8 + o], cv, s2);
        }
        ws[OW_CES + tid] = s1;
        ws[OW_CES + 4 + tid] = s2;
    }
    // pack graph to bytes
    unsigned char* gb = (unsigned char*)(ws + OW_GRAPH);
    for (int i = tid; i < 64 * MDI; i += TPB) gb[i] = (unsigned char)isrcp_i[i];
    for (int i = tid; i < 64 * MDO; i += TPB) gb[1088 + i] = (unsigned char)outdst_i[i];
    if (tid < 64) {
        gb[1024 + tid] = (unsigned char)(inslot[tid] < MDI ? inslot[tid] : MDI);
        gb[1600 + tid] = (unsigned char)(outslot[tid] < MDO ? outslot[tid] : MDO);
    }
    __syncthreads();
    if (tid == 0) {
        int mi = 0, mo = 0;
        for (int d = 0; d < 64; d++) {
            int a = gb[1024 + d], o = gb[1600 + d];
            mi = a > mi ? a : mi;
            mo = o > mo ? o : mo;
        }
        gb[1664] = (unsigned char)mi;
        gb[1665] = (unsigned char)mo;
    }
}

// ---------------------------------------------------------------------------
// Fused conv1+bn1+GAT + mean(v) + bn2+elu+pool8.  wave = head, lane = node.
//   S : stage xT (conflict-free LDS writes) + graph                  BAR
//   A : es/ed 32-tap convs; weights via wave-uniform s_loads; paired
//       LDS reads (ds_read2-friendly)
//   B : shfl softmax; cross-lane scalars packed fp16x2 -> half the
//       bpermutes (logit abs err ~1.5e-3, alpha err ~0.2%; rden scaled
//       x256 to stay fp16-normal, undone at wb store)
//   C : y[t,c] = sum_v wb[t,v]*xT[c,v]; v-halved, b128 reads         BAR
//   D : weff column -> regs (short live range), then
//       g[t,f2] = sum_k weffreg[k]*y[t,t+k] + chl[f2]*S[t]           BAR
//   E : bn2+elu+pool8 epilogue (block = exactly one pool group)
// ---------------------------------------------------------------------------
__global__ __launch_bounds__(TPB, 4) void gat_kernel(
    const float* __restrict__ x,
    const float* __restrict__ wfp,
    const float* __restrict__ chlp,
    const float* __restrict__ cesg,
    const float* __restrict__ wesg,
    const float* __restrict__ wedg,
    const float* __restrict__ bias,
    const float* __restrict__ g2, const float* __restrict__ b2,
    const float* __restrict__ m2, const float* __restrict__ v2,
    const int* __restrict__ graphi,
    float* __restrict__ pout)
{
    __shared__ __align__(16) float sm[L_TOT];
    unsigned char* gb = (unsigned char*)&sm[L_GR];

    const int tid  = threadIdx.x;
    const int b    = blockIdx.x / 192;
    const int tile = blockIdx.x % 192;
    const int t0   = tile * 8;

    const int h = tid >> 6, v = tid & 63;   // wave = head, lane = node

    // ---- S: stage graph + xT ----
    for (int idx = tid; idx < GB_INTS; idx += TPB) ((int*)&sm[L_GR])[idx] = graphi[idx];
    for (int idx = tid; idx < 2560; idx += TPB) {
        const int vv = idx & 63, j = idx >> 6;          // stride-1 LDS writes
        float val = 1.0f;
        if (j < 39) {
            const int t = t0 - 15 + j;
            val = (t >= 0 && t < Tc) ? x[(b * 64 + vv) * Tc + t] : 0.f;
        }
        sm[L_XT + j * 68 + vv] = val;
    }
    __syncthreads();

    const int hs = __builtin_amdgcn_readfirstlane(h);   // force scalar indexing
    const float* wesh = wesg + hs * 32;
    const float* wedh = wedg + hs * 32;

    // ---- Phase A: es/ed convs (register ring; paired LDS reads) ----
    float aes[8], aed[8];
    {
        const float cesh = cesg[hs], cedh = cesg[4 + hs];
        #pragma unroll
        for (int t = 0; t < 8; t++) { aes[t] = cesh; aed[t] = cedh; }
        float xr[8];
        #pragma unroll
        for (int q = 0; q < 7; q++) xr[q] = sm[L_XT + q * 68 + v];
        #pragma unroll
        for (int k = 0; k < 32; k += 2) {
            const float xa = sm[L_XT + (k + 7) * 68 + v];
            const float xb = sm[L_XT + (k + 8) * 68 + v];
            xr[(k + 7) & 7] = xa;
            {
                const float wek = wesh[k], wdk = wedh[k];
                #pragma unroll
                for (int t = 0; t < 8; t++) {
                    const float xv = xr[(k + t) & 7];
                    aes[t] = fmaf(xv, wek, aes[t]);
                    aed[t] = fmaf(xv, wdk, aed[t]);
                }
            }
            xr[(k + 8) & 7] = xb;
            {
                const float wek = wesh[k + 1], wdk = wedh[k + 1];
                #pragma unroll
                for (int t = 0; t < 8; t++) {
                    const float xv = xr[(k + 1 + t) & 7];
                    aes[t] = fmaf(xv, wek, aes[t]);
                    aed[t] = fmaf(xv, wdk, aed[t]);
                }
            }
        }
    }

    // ---- Phase B: shfl softmax with fp16x2-packed cross-lane traffic ----
    {
        // pack es pairs once (used by all in-edges)
        int aes_pk[4];
        #pragma unroll
        for (int p = 0; p < 4; p++) aes_pk[p] = pack_h2(aes[2 * p], aes[2 * p + 1]);

        const int indeg = gb[1024 + v];
        const int mdin  = gb[1664];
        float den[8] = { 0.f,0.f,0.f,0.f,0.f,0.f,0.f,0.f };
        for (int e = 0; e < mdin; e++) {
            const int s = gb[v * MDI + e];
            const float valid = (e < indeg) ? 1.f : 0.f;
            #pragma unroll
            for (int p = 0; p < 4; p++) {
                const float2 es2 = unpack_h2(__shfl(aes_pk[p], s));
                float e0 = es2.x + aed[2 * p];
                float e1 = es2.y + aed[2 * p + 1];
                e0 = e0 > 0.f ? e0 : NSLOPE * e0;
                e1 = e1 > 0.f ? e1 : NSLOPE * e1;
                den[2 * p]     += valid * __expf(e0);
                den[2 * p + 1] += valid * __expf(e1);
            }
        }
        // pack (aed, rden*256) pairs for pass 2
        int aed_pk[4], rdn_pk[4];
        #pragma unroll
        for (int p = 0; p < 4; p++) {
            aed_pk[p] = pack_h2(aed[2 * p], aed[2 * p + 1]);
            rdn_pk[p] = pack_h2(256.f / den[2 * p], 256.f / den[2 * p + 1]);
        }

        const int odeg = gb[1600 + v];
        const int mdo  = gb[1665];
        float wb[8] = { 0.f,0.f,0.f,0.f,0.f,0.f,0.f,0.f };
        for (int j = 0; j < mdo; j++) {
            const int d = gb[1088 + v * MDO + j];
            const float valid = (j < odeg) ? 1.f : 0.f;
            #pragma unroll
            for (int p = 0; p < 4; p++) {
                const float2 ed2 = unpack_h2(__shfl(aed_pk[p], d));
                const float2 rd2 = unpack_h2(__shfl(rdn_pk[p], d));
                float e0 = aes[2 * p] + ed2.x;
                float e1 = aes[2 * p + 1] + ed2.y;
                e0 = e0 > 0.f ? e0 : NSLOPE * e0;
                e1 = e1 > 0.f ? e1 : NSLOPE * e1;
                wb[2 * p]     += valid * __expf(e0) * rd2.x;
                wb[2 * p + 1] += valid * __expf(e1) * rd2.y;
            }
        }
        #pragma unroll
        for (int t = 0; t < 8; t++)
            sm[L_WB + h * 544 + t * 68 + v] = wb[t] * (1.f / 256.f);
    }
    __asm__ volatile("s_waitcnt lgkmcnt(0)" ::: "memory");   // wave-local drain

    // ---- Phase C: y[t,c] = sum_v wb[t,v]*xT[c,v], v-halved ----
    {
        const int vh = v >> 5, tp = (v >> 3) & 3, cg = v & 7;
        float ya[2][5] = { { 0.f,0.f,0.f,0.f,0.f }, { 0.f,0.f,0.f,0.f,0.f } };
        const float* xbase = &sm[L_XT + cg * 5 * 68 + vh * 32];
        const float* wb0   = &sm[L_WB + h * 544 + (2 * tp) * 68 + vh * 32];
        #pragma unroll
        for (int v4 = 0; v4 < 8; v4++) {
            const float4 wa = *(const float4*)(wb0 + v4 * 4);
            const float4 wbv = *(const float4*)(wb0 + 68 + v4 * 4);
            #pragma unroll
            for (int q = 0; q < 5; q++) {
                const float4 x4 = *(const float4*)(xbase + q * 68 + v4 * 4);
                ya[0][q] = fmaf(wa.x, x4.x, fmaf(wa.y, x4.y,
                           fmaf(wa.z, x4.z, fmaf(wa.w, x4.w, ya[0][q]))));
                ya[1][q] = fmaf(wbv.x, x4.x, fmaf(wbv.y, x4.y,
                           fmaf(wbv.z, x4.z, fmaf(wbv.w, x4.w, ya[1][q]))));
            }
        }
        #pragma unroll
        for (int i = 0; i < 2; i++)
            #pragma unroll
            for (int q = 0; q < 5; q++)
                ya[i][q] += __shfl_xor(ya[i][q], 32);
        if (vh == 0) {
            float* yr = &sm[L_Y + h * 328 + (2 * tp) * 41 + cg * 5];
            #pragma unroll
            for (int i = 0; i < 2; i++)
                #pragma unroll
                for (int q = 0; q < 5; q++)
                    yr[i * 41 + q] = ya[i][q];
        }
    }
    // Block barrier: all waves done with phases B/C (graph bytes now dead)
    // before G (which aliases them) is written.
    __syncthreads();

    // ---- Phase D: load weff column NOW (short live range -> registers),
    //      then g[t,f2] = sum_k weffreg[k]*y[t,t+k] + chl[f2]*S[t] ----
    {
        const int f2d = h * 8 + (v & 7);
        float wfr[32];
        #pragma unroll
        for (int k = 0; k < 32; k++) wfr[k] = wfp[k * 32 + f2d];
        const float chld = chlp[f2d];

        const int t = v >> 3;
        const float* yr = &sm[L_Y + h * 328 + t * 41];
        float acc = chld * yr[39];
        #pragma unroll
        for (int k = 0; k < 32; k++)
            acc = fmaf(wfr[k], yr[t + k], acc);
        sm[L_G + t * 36 + f2d] = acc;    // stride 36: <=2-way banks; dead graph bytes
    }
    __syncthreads();

    // ---- Epilogue: bn2 + elu + pool8 (block = one pool group) ----
    if (tid < 32) {
        const float a2 = g2[tid] * rsqrtf(v2[tid] + EPSc);
        const float c2 = b2[tid] + a2 * (bias[tid] - m2[tid]);
        float s = 0.f;
        #pragma unroll
        for (int t = 0; t < 8; t++) {
            const float gv = sm[L_G + t * 36 + tid] * (1.f / 64.f);
            const float y = fmaf(a2, gv, c2);
            s += y > 0.f ? y : __expf(y) - 1.f;
        }
        pout[(b * T2c + tile) * 32 + tid] = s * 0.125f;
    }
}

// ---------------------------------------------------------------------------
// conv3(K=16,'same') + bn3 + elu + avgpool(4): p[B,192,32] -> out[B,32,48].
// Weights read straight from global (k-contiguous float4; 64 KB L2/L1-hot,
// shared by all blocks) — only p staged in LDS.
// ---------------------------------------------------------------------------
__global__ __launch_bounds__(TPB) void conv3_kernel(const float* __restrict__ pp,
                                                    const float* __restrict__ w3,
                                                    const float* __restrict__ g3,
                                                    const float* __restrict__ b3,
                                                    const float* __restrict__ m3,
                                                    const float* __restrict__ v3,
                                                    float* __restrict__ outp)
{
    __shared__ float pl[63 * 32];
    __shared__ float q[48 * 32];
    const int tid = threadIdx.x;
    const int b = blockIdx.x >> 2, cc = blockIdx.x & 3;

    for (int idx = tid; idx < 63 * 32; idx += TPB) {
        int r = idx >> 5, f2 = idx & 31;
        int tog = cc * 48 - 7 + r;
        pl[idx] = (tog >= 0 && tog < T2c) ? pp[(b * T2c + tog) * 32 + f2] : 0.f;
    }
    __syncthreads();

    const int f2o = tid & 31, grp = tid >> 5;
    const int tb = grp * 6;
    float acc[6] = { 0.f, 0.f, 0.f, 0.f, 0.f, 0.f };
    for (int f2i = 0; f2i < 32; f2i++) {
        float seg[21];
        #pragma unroll
        for (int r = 0; r < 21; r++) seg[r] = pl[(tb + r) * 32 + f2i];
        const float4* wrow = (const float4*)(w3 + (f2o * 32 + f2i) * 16);
        #pragma unroll
        for (int k4 = 0; k4 < 4; k4++) {
            const float4 w4 = wrow[k4];
            #pragma unroll
            for (int j = 0; j < 6; j++) {
                acc[j] = fmaf(seg[j + k4 * 4 + 0], w4.x,
                         fmaf(seg[j + k4 * 4 + 1], w4.y,
                         fmaf(seg[j + k4 * 4 + 2], w4.z,
                         fmaf(seg[j + k4 * 4 + 3], w4.w, acc[j]))));
            }
        }
    }
    const float a3 = g3[f2o] * rsqrtf(v3[f2o] + EPSc);
    const float c3 = b3[f2o] - a3 * m3[f2o];
    #pragma unroll
    for (int j = 0; j < 6; j++) {
        float y = fmaf(a3, acc[j], c3);
        y = y > 0.f ? y : __expf(y) - 1.f;
        q[(tb + j) * 32 + f2o] = y;
    }
    __syncthreads();
    for (int idx = tid; idx < 12 * 32; idx += TPB) {
        int t4 = idx >> 5, f2 = idx & 31;
        int r0 = t4 * 4;
        float s = q[r0 * 32 + f2] + q[(r0 + 1) * 32 + f2] +
                  q[(r0 + 2) * 32 + f2] + q[(r0 + 3) * 32 + f2];
        outp[(b * 32 + f2) * 48 + cc * 12 + t4] = s * 0.25f;
    }
}

// ---------------------------------------------------------------------------
extern "C" void kernel_launch(void* const* d_in, const int* in_sizes, int n_in,
                              void* d_out, int out_size, void* d_ws, size_t ws_size,
                              hipStream_t stream)
{
    const float* x    = (const float*)d_in[0];
    const float* c1w  = (const float*)d_in[1];
    const float* g1   = (const float*)d_in[2];
    const float* b1   = (const float*)d_in[3];
    const float* m1   = (const float*)d_in[4];
    const float* v1   = (const float*)d_in[5];
    const float* W    = (const float*)d_in[6];
    const float* asrc = (const float*)d_in[7];
    const float* adst = (const float*)d_in[8];
    const float* bias = (const float*)d_in[9];
    const float* g2   = (const float*)d_in[10];
    const float* b2   = (const float*)d_in[11];
    const float* m2   = (const float*)d_in[12];
    const float* v2   = (const float*)d_in[13];
    const float* w3   = (const float*)d_in[14];
    const float* g3   = (const float*)d_in[15];
    const float* b3   = (const float*)d_in[16];
    const float* m3   = (const float*)d_in[17];
    const float* v3   = (const float*)d_in[18];
    const int*   ei   = (const int*)d_in[19];
    const int    ne   = in_sizes[19] / 2;

    float* ws = (float*)d_ws;

    prep_kernel<<<1, TPB, 0, stream>>>(c1w, g1, b1, m1, v1, W, asrc, adst,
                                       ei, ne, ws);

    gat_kernel<<<Bc * T2c, TPB, 0, stream>>>(x,
                                             ws + OW_WEFF, ws + OW_CHL,
                                             ws + OW_CES,
                                             ws + OW_WES, ws + OW_WED,
                                             bias, g2, b2, m2, v2,
                                             (const int*)(ws + OW_GRAPH),
                                             ws + OW_P);

    conv3_kernel<<<Bc * 4, TPB, 0, stream>>>(ws + OW_P, w3, g3, b3, m3, v3,
                                             (float*)d_out);
}

// Round 14
// 170.875 us; speedup vs baseline: 1.0155x; 1.0155x over previous
//
#include <hip/hip_runtime.h>
#include <math.h>

#define TPB 256

// Problem constants
constexpr int Bc = 16, Tc = 1536;
constexpr int T2c = 192;           // T / P1
constexpr float EPSc = 1e-5f;
constexpr float NSLOPE = 0.2f;
constexpr int MDI = 16;            // padded in-degree stride (bytes)
constexpr int MDO = 8;             // padded out-degree stride (bytes)

// Workspace layout (float offsets)
constexpr int OW_WEFF = 0;         // [32 k][32 f2]
constexpr int OW_CHL  = 1024;      // [32]
constexpr int OW_CES  = 1056;      // ces[4] | ced[4]
constexpr int OW_WES  = 1064;      // [4 h][32 k]   (h-major: wave-uniform s_load)
constexpr int OW_WED  = 1192;      // [4 h][32 k]
constexpr int OW_A2C2 = 1320;      // a2[32] | c2[32] folded bn2 affine
constexpr int OW_GRAPH= 1384;      // 417 ints packed byte graph
constexpr int OW_P    = 1801;      // [B][192][32]

// Packed graph byte offsets:
//   [0,1024)    in-lists  isrc[d*16+e]  (pad 0)
//   [1024,1088) indeg[d]  (clamped)
//   [1088,1600) out-lists outdst[v*8+j] (pad 0)
//   [1600,1664) outdeg[v] (clamped)
//   [1664] max in-degree   [1665] max out-degree
constexpr int GB_INTS = 417;

// gat LDS layout (float offsets)
constexpr int L_XT  = 0;           // xT [40 c][68 v]; row 39 = ones (S column)
constexpr int L_WB  = 2720;        // [4 h][8 t][68 v]
constexpr int L_Y   = 4896;        // [4 h][8 t][41]
constexpr int L_GR  = 6208;        // 417 ints packed graph
constexpr int L_TOT = 6625;        // 26.5 KB -> 6 blocks/CU

// ---------------------------------------------------------------------------
// Prep (1 block): fold bn1+gatW+conv1 -> weff/chl; es/ed conv weights in
// [h][k] layout; bn2 affine (gat bias folded); packed byte graph.
// ---------------------------------------------------------------------------
__global__ void prep_kernel(const float* __restrict__ c1w,
                            const float* __restrict__ g1, const float* __restrict__ b1,
                            const float* __restrict__ m1, const float* __restrict__ v1,
                            const float* __restrict__ W,
                            const float* __restrict__ asrc, const float* __restrict__ adst,
                            const float* __restrict__ bias,
                            const float* __restrict__ g2, const float* __restrict__ b2,
                            const float* __restrict__ m2, const float* __restrict__ v2,
                            const int* __restrict__ ei, int ne, float* __restrict__ ws)
{
    const int tid = threadIdx.x;
    __shared__ float sweff[1024];
    __shared__ float schl[32];
    __shared__ int isrcp_i[64 * MDI];
    __shared__ int outdst_i[64 * MDO];
    __shared__ int inslot[64], outslot[64];

    // weff[k*32+f2] = sum_f a1[f]*W[f,f2]*w1[f,k]
    for (int idx = tid; idx < 1024; idx += TPB) {
        int k = idx >> 5, f2 = idx & 31;
        float s = 0.f;
        for (int f = 0; f < 16; f++) {
            float a1 = g1[f] * rsqrtf(v1[f] + EPSc);
            s += a1 * W[f * 32 + f2] * c1w[f * 32 + k];
        }
        ws[OW_WEFF + idx] = s;
        sweff[idx] = s;
    }
    for (int f2 = tid; f2 < 32; f2 += TPB) {
        float s = 0.f;
        for (int f = 0; f < 16; f++) {
            float a1 = g1[f] * rsqrtf(v1[f] + EPSc);
            s = fmaf(b1[f] - a1 * m1[f], W[f * 32 + f2], s);
        }
        ws[OW_CHL + f2] = s;
        schl[f2] = s;
        float a2 = g2[f2] * rsqrtf(v2[f2] + EPSc);
        ws[OW_A2C2 + f2] = a2;
        ws[OW_A2C2 + 32 + f2] = b2[f2] + a2 * (bias[f2] - m2[f2]);
    }

    // graph: padded in/out lists (LDS atomics)
    for (int i = tid; i < 64 * MDI; i += TPB) isrcp_i[i] = 0;
    for (int i = tid; i < 64 * MDO; i += TPB) outdst_i[i] = 0;
    if (tid < 64) { inslot[tid] = 0; outslot[tid] = 0; }
    __syncthreads();
    for (int e = tid; e < ne; e += TPB) {
        int s = ei[e], d = ei[ne + e];
        int pi = atomicAdd(&inslot[d], 1);
        if (pi < MDI) isrcp_i[d * MDI + pi] = s;
        int po = atomicAdd(&outslot[s], 1);
        if (po < MDO) outdst_i[s * MDO + po] = d;
    }
    __syncthreads();

    // wes/wed in [h][k] layout + ces/ced
    if (tid < 128) {
        int k = tid >> 2, h = tid & 3;
        float s1 = 0.f, s2 = 0.f;
        for (int o = 0; o < 8; o++) {
            float wv = sweff[k * 32 + h * 8 + o];
            s1 = fmaf(asrc[h * 8 + o], wv, s1);
            s2 = fmaf(adst[h * 8 + o], wv, s2);
        }
        ws[OW_WES + h * 32 + k] = s1;
        ws[OW_WED + h * 32 + k] = s2;
    }
    if (tid < 4) {
        float s1 = 0.f, s2 = 0.f;
        for (int o = 0; o < 8; o++) {
            float cv = schl[tid * 8 + o];
            s1 = fmaf(asrc[tid * 8 + o], cv, s1);
            s2 = fmaf(adst[tid * 8 + o], cv, s2);
        }
        ws[OW_CES + tid] = s1;
        ws[OW_CES + 4 + tid] = s2;
    }
    // pack graph to bytes
    unsigned char* gb = (unsigned char*)(ws + OW_GRAPH);
    for (int i = tid; i < 64 * MDI; i += TPB) gb[i] = (unsigned char)isrcp_i[i];
    for (int i = tid; i < 64 * MDO; i += TPB) gb[1088 + i] = (unsigned char)outdst_i[i];
    if (tid < 64) {
        gb[1024 + tid] = (unsigned char)(inslot[tid] < MDI ? inslot[tid] : MDI);
        gb[1600 + tid] = (unsigned char)(outslot[tid] < MDO ? outslot[tid] : MDO);
    }
    __syncthreads();
    if (tid == 0) {
        int mi = 0, mo = 0;
        for (int d = 0; d < 64; d++) {
            int a = gb[1024 + d], o = gb[1600 + d];
            mi = a > mi ? a : mi;
            mo = o > mo ? o : mo;
        }
        gb[1664] = (unsigned char)mi;
        gb[1665] = (unsigned char)mo;
    }
}

// ---------------------------------------------------------------------------
// Fused conv1+bn1+GAT + mean(v) + bn2+elu+pool8.  wave = head, lane = node.
//   S : stage xT (conflict-free LDS writes) + graph                  BAR
//   A : es/ed 32-tap convs; weights via wave-uniform s_loads
//   B : fp32 shfl softmax over byte adjacency -> wb[t][v]
//   C : y[t,c] = sum_v wb[t,v]*xT[c,v]; v-halved, b128 reads         BAR
//   D+E fused, wave-local: lane (t,o) computes g, applies bn2+elu,
//       then shfl_xor-reduces over t (lane bits [5:3]); lanes v<8 of
//       wave h write pout[f2 = h*8+v]. No G array, no final barrier.
// ---------------------------------------------------------------------------
__global__ __launch_bounds__(TPB, 4) void gat_kernel(
    const float* __restrict__ x,
    const float* __restrict__ wfp,
    const float* __restrict__ chlp,
    const float* __restrict__ cesg,
    const float* __restrict__ wesg,
    const float* __restrict__ wedg,
    const float* __restrict__ a2c2,
    const int* __restrict__ graphi,
    float* __restrict__ pout)
{
    __shared__ __align__(16) float sm[L_TOT];
    unsigned char* gb = (unsigned char*)&sm[L_GR];

    const int tid  = threadIdx.x;
    const int b    = blockIdx.x / 192;
    const int tile = blockIdx.x % 192;
    const int t0   = tile * 8;

    const int h = tid >> 6, v = tid & 63;   // wave = head, lane = node

    // ---- S: stage graph + xT ----
    for (int idx = tid; idx < GB_INTS; idx += TPB) ((int*)&sm[L_GR])[idx] = graphi[idx];
    for (int idx = tid; idx < 2560; idx += TPB) {
        const int vv = idx & 63, j = idx >> 6;          // stride-1 LDS writes
        float val = 1.0f;
        if (j < 39) {
            const int t = t0 - 15 + j;
            val = (t >= 0 && t < Tc) ? x[(b * 64 + vv) * Tc + t] : 0.f;
        }
        sm[L_XT + j * 68 + vv] = val;
    }
    __syncthreads();

    const int hs = __builtin_amdgcn_readfirstlane(h);   // force scalar indexing
    const float* wesh = wesg + hs * 32;
    const float* wedh = wedg + hs * 32;

    // ---- Phase A: es/ed convs (register ring; weights via s_load) ----
    float aes[8], aed[8];
    {
        const float cesh = cesg[hs], cedh = cesg[4 + hs];
        #pragma unroll
        for (int t = 0; t < 8; t++) { aes[t] = cesh; aed[t] = cedh; }
        float xr[8];
        #pragma unroll
        for (int q = 0; q < 7; q++) xr[q] = sm[L_XT + q * 68 + v];
        #pragma unroll
        for (int k = 0; k < 32; k++) {
            xr[(k + 7) & 7] = sm[L_XT + (k + 7) * 68 + v];
            const float wek = wesh[k];
            const float wdk = wedh[k];
            #pragma unroll
            for (int t = 0; t < 8; t++) {
                const float xv = xr[(k + t) & 7];
                aes[t] = fmaf(xv, wek, aes[t]);
                aed[t] = fmaf(xv, wdk, aed[t]);
            }
        }
    }

    // ---- Phase B: fp32 shfl softmax (no max-shift: logits O(1), exact) ----
    {
        const int indeg = gb[1024 + v];
        const int mdin  = gb[1664];
        float den[8] = { 0.f,0.f,0.f,0.f,0.f,0.f,0.f,0.f };
        for (int e = 0; e < mdin; e++) {
            const int s = gb[v * MDI + e];
            const float valid = (e < indeg) ? 1.f : 0.f;
            #pragma unroll
            for (int t = 0; t < 8; t++) {
                float ev = __shfl(aes[t], s) + aed[t];
                ev = ev > 0.f ? ev : NSLOPE * ev;
                den[t] += valid * __expf(ev);
            }
        }
        float rden[8];
        #pragma unroll
        for (int t = 0; t < 8; t++) rden[t] = 1.f / den[t];

        const int odeg = gb[1600 + v];
        const int mdo  = gb[1665];
        float wb[8] = { 0.f,0.f,0.f,0.f,0.f,0.f,0.f,0.f };
        for (int j = 0; j < mdo; j++) {
            const int d = gb[1088 + v * MDO + j];
            const float valid = (j < odeg) ? 1.f : 0.f;
            #pragma unroll
            for (int t = 0; t < 8; t++) {
                float ev = aes[t] + __shfl(aed[t], d);
                ev = ev > 0.f ? ev : NSLOPE * ev;
                wb[t] += valid * __expf(ev) * __shfl(rden[t], d);
            }
        }
        #pragma unroll
        for (int t = 0; t < 8; t++) sm[L_WB + h * 544 + t * 68 + v] = wb[t];
    }
    __asm__ volatile("s_waitcnt lgkmcnt(0)" ::: "memory");   // wave-local drain

    // ---- Phase C: y[t,c] = sum_v wb[t,v]*xT[c,v], v-halved ----
    {
        const int vh = v >> 5, tp = (v >> 3) & 3, cg = v & 7;
        float ya[2][5] = { { 0.f,0.f,0.f,0.f,0.f }, { 0.f,0.f,0.f,0.f,0.f } };
        const float* xbase = &sm[L_XT + cg * 5 * 68 + vh * 32];
        const float* wb0   = &sm[L_WB + h * 544 + (2 * tp) * 68 + vh * 32];
        #pragma unroll
        for (int v4 = 0; v4 < 8; v4++) {
            const float4 wa = *(const float4*)(wb0 + v4 * 4);
            const float4 wbv = *(const float4*)(wb0 + 68 + v4 * 4);
            #pragma unroll
            for (int q = 0; q < 5; q++) {
                const float4 x4 = *(const float4*)(xbase + q * 68 + v4 * 4);
                ya[0][q] = fmaf(wa.x, x4.x, fmaf(wa.y, x4.y,
                           fmaf(wa.z, x4.z, fmaf(wa.w, x4.w, ya[0][q]))));
                ya[1][q] = fmaf(wbv.x, x4.x, fmaf(wbv.y, x4.y,
                           fmaf(wbv.z, x4.z, fmaf(wbv.w, x4.w, ya[1][q]))));
            }
        }
        #pragma unroll
        for (int i = 0; i < 2; i++)
            #pragma unroll
            for (int q = 0; q < 5; q++)
                ya[i][q] += __shfl_xor(ya[i][q], 32);
        if (vh == 0) {
            float* yr = &sm[L_Y + h * 328 + (2 * tp) * 41 + cg * 5];
            #pragma unroll
            for (int i = 0; i < 2; i++)
                #pragma unroll
                for (int q = 0; q < 5; q++)
                    yr[i * 41 + q] = ya[i][q];
        }
    }
    // All waves must finish phase C's y-writes before D reads them? No —
    // wave h reads only its own L_Y region (wave-local); drain suffices.
    __asm__ volatile("s_waitcnt lgkmcnt(0)" ::: "memory");

    // ---- Phase D+E fused (wave-local): g -> bn2+elu -> pool8 via shfl ----
    {
        const int t = v >> 3, o = v & 7;
        const int f2d = h * 8 + o;
        float wfr[32];
        #pragma unroll
        for (int k = 0; k < 32; k++) wfr[k] = wfp[k * 32 + f2d];

        const float* yr = &sm[L_Y + h * 328 + t * 41];
        float acc = chlp[f2d] * yr[39];
        #pragma unroll
        for (int k = 0; k < 32; k++)
            acc = fmaf(wfr[k], yr[t + k], acc);

        // bn2 + elu on this (t, f2) element; then reduce over t (lane bits 5:3)
        const float a2 = a2c2[f2d], c2 = a2c2[32 + f2d];
        float y = fmaf(a2, acc * (1.f / 64.f), c2);
        y = y > 0.f ? y : __expf(y) - 1.f;
        y += __shfl_xor(y, 8);
        y += __shfl_xor(y, 16);
        y += __shfl_xor(y, 32);
        if (v < 8)
            pout[(b * T2c + tile) * 32 + h * 8 + v] = y * 0.125f;
    }
}

// ---------------------------------------------------------------------------
// conv3(K=16,'same') + bn3 + elu + avgpool(4): p[B,192,32] -> out[B,32,48].
// Weights read straight from global (k-contiguous float4; L2/L1-hot).
// ---------------------------------------------------------------------------
__global__ __launch_bounds__(TPB) void conv3_kernel(const float* __restrict__ pp,
                                                    const float* __restrict__ w3,
                                                    const float* __restrict__ g3,
                                                    const float* __restrict__ b3,
                                                    const float* __restrict__ m3,
                                                    const float* __restrict__ v3,
                                                    float* __restrict__ outp)
{
    __shared__ float pl[63 * 32];
    __shared__ float q[48 * 32];
    const int tid = threadIdx.x;
    const int b = blockIdx.x >> 2, cc = blockIdx.x & 3;

    for (int idx = tid; idx < 63 * 32; idx += TPB) {
        int r = idx >> 5, f2 = idx & 31;
        int tog = cc * 48 - 7 + r;
        pl[idx] = (tog >= 0 && tog < T2c) ? pp[(b * T2c + tog) * 32 + f2] : 0.f;
    }
    __syncthreads();

    const int f2o = tid & 31, grp = tid >> 5;
    const int tb = grp * 6;
    float acc[6] = { 0.f, 0.f, 0.f, 0.f, 0.f, 0.f };
    for (int f2i = 0; f2i < 32; f2i++) {
        float seg[21];
        #pragma unroll
        for (int r = 0; r < 21; r++) seg[r] = pl[(tb + r) * 32 + f2i];
        const float4* wrow = (const float4*)(w3 + (f2o * 32 + f2i) * 16);
        #pragma unroll
        for (int k4 = 0; k4 < 4; k4++) {
            const float4 w4 = wrow[k4];
            #pragma unroll
            for (int j = 0; j < 6; j++) {
                acc[j] = fmaf(seg[j + k4 * 4 + 0], w4.x,
                         fmaf(seg[j + k4 * 4 + 1], w4.y,
                         fmaf(seg[j + k4 * 4 + 2], w4.z,
                         fmaf(seg[j + k4 * 4 + 3], w4.w, acc[j]))));
            }
        }
    }
    const float a3 = g3[f2o] * rsqrtf(v3[f2o] + EPSc);
    const float c3 = b3[f2o] - a3 * m3[f2o];
    #pragma unroll
    for (int j = 0; j < 6; j++) {
        float y = fmaf(a3, acc[j], c3);
        y = y > 0.f ? y : __expf(y) - 1.f;
        q[(tb + j) * 32 + f2o] = y;
    }
    __syncthreads();
    for (int idx = tid; idx < 12 * 32; idx += TPB) {
        int t4 = idx >> 5, f2 = idx & 31;
        int r0 = t4 * 4;
        float s = q[r0 * 32 + f2] + q[(r0 + 1) * 32 + f2] +
                  q[(r0 + 2) * 32 + f2] + q[(r0 + 3) * 32 + f2];
        outp[(b * 32 + f2) * 48 + cc * 12 + t4] = s * 0.25f;
    }
}

// ---------------------------------------------------------------------------
extern "C" void kernel_launch(void* const* d_in, const int* in_sizes, int n_in,
                              void* d_out, int out_size, void* d_ws, size_t ws_size,
                              hipStream_t stream)
{
    const float* x    = (const float*)d_in[0];
    const float* c1w  = (const float*)d_in[1];
    const float* g1   = (const float*)d_in[2];
    const float* b1   = (const float*)d_in[3];
    const float* m1   = (const float*)d_in[4];
    const float* v1   = (const float*)d_in[5];
    const float* W    = (const float*)d_in[6];
    const float* asrc = (const float*)d_in[7];
    const float* adst = (const float*)d_in[8];
    const float* bias = (const float*)d_in[9];
    const float* g2   = (const float*)d_in[10];
    const float* b2   = (const float*)d_in[11];
    const float* m2   = (const float*)d_in[12];
    const float* v2   = (const float*)d_in[13];
    const float* w3   = (const float*)d_in[14];
    const float* g3   = (const float*)d_in[15];
    const float* b3   = (const float*)d_in[16];
    const float* m3   = (const float*)d_in[17];
    const float* v3   = (const float*)d_in[18];
    const int*   ei   = (const int*)d_in[19];
    const int    ne   = in_sizes[19] / 2;

    float* ws = (float*)d_ws;

    prep_kernel<<<1, TPB, 0, stream>>>(c1w, g1, b1, m1, v1, W, asrc, adst,
                                       bias, g2, b2, m2, v2, ei, ne, ws);

    gat_kernel<<<Bc * T2c, TPB, 0, stream>>>(x,
                                             ws + OW_WEFF, ws + OW_CHL,
                                             ws + OW_CES,
                                             ws + OW_WES, ws + OW_WED,
                                             ws + OW_A2C2,
                                             (const int*)(ws + OW_GRAPH),
                                             ws + OW_P);

    conv3_kernel<<<Bc * 4, TPB, 0, stream>>>(ws + OW_P, w3, g3, b3, m3, v3,
                                             (float*)d_out);
}

// Round 15
// 165.842 us; speedup vs baseline: 1.0463x; 1.0303x over previous
//
#include <hip/hip_runtime.h>
#include <math.h>

#define TPB 256

// Problem constants
constexpr int Bc = 16, Tc = 1536;
constexpr int T2c = 192;           // T / P1
constexpr float EPSc = 1e-5f;
constexpr float NSLOPE = 0.2f;
constexpr int MDI = 16;            // padded in-degree stride (bytes)
constexpr int MDO = 8;             // padded out-degree stride (bytes)

// Workspace layout (float offsets)
constexpr int OW_WEFF = 0;         // [32 k][32 f2]
constexpr int OW_CHL  = 1024;      // [32]
constexpr int OW_CES  = 1056;      // ces[4] | ced[4]
constexpr int OW_WES  = 1064;      // [4 h][32 k]   (h-major: wave-uniform s_load)
constexpr int OW_WED  = 1192;      // [4 h][32 k]
constexpr int OW_A2C2 = 1320;      // a2[32] | c2[32] folded bn2 affine
constexpr int OW_GRAPH= 1384;      // 417 ints packed byte graph
constexpr int OW_P    = 1801;      // [B][192][32]

// Packed graph byte offsets:
//   [0,1024)    in-lists  isrc[d*16+e]  (pad 0)
//   [1024,1088) indeg[d]  (clamped)
//   [1088,1600) out-lists outdst[v*8+j] (pad 0)
//   [1600,1664) outdeg[v] (clamped)
//   [1664] max in-degree   [1665] max out-degree
constexpr int GB_INTS = 417;

// gat LDS layout (float offsets)
constexpr int L_XT  = 0;           // xT [40 c][68 v]; row 39 = ones (S column)
constexpr int L_WB  = 2720;        // [4 h][8 t][68 v]
constexpr int L_Y   = 4896;        // [4 h][8 t][41]
constexpr int L_GR  = 6208;        // 417 ints packed graph
constexpr int L_TOT = 6625;        // 26.5 KB -> 6 blocks/CU

// ---------------------------------------------------------------------------
// Prep (1 block): fold bn1+gatW+conv1 -> weff/chl; es/ed conv weights in
// [h][k] layout; bn2 affine (gat bias folded); packed byte graph.
// ---------------------------------------------------------------------------
__global__ void prep_kernel(const float* __restrict__ c1w,
                            const float* __restrict__ g1, const float* __restrict__ b1,
                            const float* __restrict__ m1, const float* __restrict__ v1,
                            const float* __restrict__ W,
                            const float* __restrict__ asrc, const float* __restrict__ adst,
                            const float* __restrict__ bias,
                            const float* __restrict__ g2, const float* __restrict__ b2,
                            const float* __restrict__ m2, const float* __restrict__ v2,
                            const int* __restrict__ ei, int ne, float* __restrict__ ws)
{
    const int tid = threadIdx.x;
    __shared__ float sweff[1024];
    __shared__ float schl[32];
    __shared__ int isrcp_i[64 * MDI];
    __shared__ int outdst_i[64 * MDO];
    __shared__ int inslot[64], outslot[64];

    // weff[k*32+f2] = sum_f a1[f]*W[f,f2]*w1[f,k]
    for (int idx = tid; idx < 1024; idx += TPB) {
        int k = idx >> 5, f2 = idx & 31;
        float s = 0.f;
        for (int f = 0; f < 16; f++) {
            float a1 = g1[f] * rsqrtf(v1[f] + EPSc);
            s += a1 * W[f * 32 + f2] * c1w[f * 32 + k];
        }
        ws[OW_WEFF + idx] = s;
        sweff[idx] = s;
    }
    for (int f2 = tid; f2 < 32; f2 += TPB) {
        float s = 0.f;
        for (int f = 0; f < 16; f++) {
            float a1 = g1[f] * rsqrtf(v1[f] + EPSc);
            s = fmaf(b1[f] - a1 * m1[f], W[f * 32 + f2], s);
        }
        ws[OW_CHL + f2] = s;
        schl[f2] = s;
        float a2 = g2[f2] * rsqrtf(v2[f2] + EPSc);
        ws[OW_A2C2 + f2] = a2;
        ws[OW_A2C2 + 32 + f2] = b2[f2] + a2 * (bias[f2] - m2[f2]);
    }

    // graph: padded in/out lists (LDS atomics)
    for (int i = tid; i < 64 * MDI; i += TPB) isrcp_i[i] = 0;
    for (int i = tid; i < 64 * MDO; i += TPB) outdst_i[i] = 0;
    if (tid < 64) { inslot[tid] = 0; outslot[tid] = 0; }
    __syncthreads();
    for (int e = tid; e < ne; e += TPB) {
        int s = ei[e], d = ei[ne + e];
        int pi = atomicAdd(&inslot[d], 1);
        if (pi < MDI) isrcp_i[d * MDI + pi] = s;
        int po = atomicAdd(&outslot[s], 1);
        if (po < MDO) outdst_i[s * MDO + po] = d;
    }
    __syncthreads();

    // wes/wed in [h][k] layout + ces/ced
    if (tid < 128) {
        int k = tid >> 2, h = tid & 3;
        float s1 = 0.f, s2 = 0.f;
        for (int o = 0; o < 8; o++) {
            float wv = sweff[k * 32 + h * 8 + o];
            s1 = fmaf(asrc[h * 8 + o], wv, s1);
            s2 = fmaf(adst[h * 8 + o], wv, s2);
        }
        ws[OW_WES + h * 32 + k] = s1;
        ws[OW_WED + h * 32 + k] = s2;
    }
    if (tid < 4) {
        float s1 = 0.f, s2 = 0.f;
        for (int o = 0; o < 8; o++) {
            float cv = schl[tid * 8 + o];
            s1 = fmaf(asrc[tid * 8 + o], cv, s1);
            s2 = fmaf(adst[tid * 8 + o], cv, s2);
        }
        ws[OW_CES + tid] = s1;
        ws[OW_CES + 4 + tid] = s2;
    }
    // pack graph to bytes
    unsigned char* gb = (unsigned char*)(ws + OW_GRAPH);
    for (int i = tid; i < 64 * MDI; i += TPB) gb[i] = (unsigned char)isrcp_i[i];
    for (int i = tid; i < 64 * MDO; i += TPB) gb[1088 + i] = (unsigned char)outdst_i[i];
    if (tid < 64) {
        gb[1024 + tid] = (unsigned char)(inslot[tid] < MDI ? inslot[tid] : MDI);
        gb[1600 + tid] = (unsigned char)(outslot[tid] < MDO ? outslot[tid] : MDO);
    }
    __syncthreads();
    if (tid == 0) {
        int mi = 0, mo = 0;
        for (int d = 0; d < 64; d++) {
            int a = gb[1024 + d], o = gb[1600 + d];
            mi = a > mi ? a : mi;
            mo = o > mo ? o : mo;
        }
        gb[1664] = (unsigned char)mi;
        gb[1665] = (unsigned char)mo;
    }
}

// ---------------------------------------------------------------------------
// Fused conv1+bn1+GAT + mean(v) + bn2+elu+pool8.  wave = head, lane = node.
//   S : stage xT — COALESCED global reads (lane-major over t), transposed
//       LDS writes (8-way conflict on ~10 write insts: cheap)        BAR
//   A : es/ed 32-tap convs; weights via wave-uniform s_loads
//   B : fp32 shfl softmax over byte adjacency -> wb[t][v]
//   C : y[t,c] = sum_v wb[t,v]*xT[c,v]; v-halved, b128 reads
//   D+E fused, wave-local: g -> bn2+elu -> pool8 via shfl; lanes v<8
//       of wave h write pout[f2 = h*8+v]. No G array, no final barrier.
// ---------------------------------------------------------------------------
__global__ __launch_bounds__(TPB, 4) void gat_kernel(
    const float* __restrict__ x,
    const float* __restrict__ wfp,
    const float* __restrict__ chlp,
    const float* __restrict__ cesg,
    const float* __restrict__ wesg,
    const float* __restrict__ wedg,
    const float* __restrict__ a2c2,
    const int* __restrict__ graphi,
    float* __restrict__ pout)
{
    __shared__ __align__(16) float sm[L_TOT];
    unsigned char* gb = (unsigned char*)&sm[L_GR];

    const int tid  = threadIdx.x;
    const int b    = blockIdx.x / 192;
    const int tile = blockIdx.x % 192;
    const int t0   = tile * 8;

    const int h = tid >> 6, v = tid & 63;   // wave = head, lane = node

    // ---- S: stage graph + xT (coalesced global, transposed LDS writes) ----
    for (int idx = tid; idx < GB_INTS; idx += TPB) ((int*)&sm[L_GR])[idx] = graphi[idx];
    for (int idx = tid; idx < 2560; idx += TPB) {
        const int vv = idx / 40, j = idx % 40;   // consecutive lanes: consecutive t
        float val = 1.0f;
        if (j < 39) {
            const int t = t0 - 15 + j;
            val = (t >= 0 && t < Tc) ? x[(b * 64 + vv) * Tc + t] : 0.f;
        }
        sm[L_XT + j * 68 + vv] = val;
    }
    __syncthreads();

    const int hs = __builtin_amdgcn_readfirstlane(h);   // force scalar indexing
    const float* wesh = wesg + hs * 32;
    const float* wedh = wedg + hs * 32;

    // ---- Phase A: es/ed convs (register ring; weights via s_load) ----
    float aes[8], aed[8];
    {
        const float cesh = cesg[hs], cedh = cesg[4 + hs];
        #pragma unroll
        for (int t = 0; t < 8; t++) { aes[t] = cesh; aed[t] = cedh; }
        float xr[8];
        #pragma unroll
        for (int q = 0; q < 7; q++) xr[q] = sm[L_XT + q * 68 + v];
        #pragma unroll
        for (int k = 0; k < 32; k++) {
            xr[(k + 7) & 7] = sm[L_XT + (k + 7) * 68 + v];
            const float wek = wesh[k];
            const float wdk = wedh[k];
            #pragma unroll
            for (int t = 0; t < 8; t++) {
                const float xv = xr[(k + t) & 7];
                aes[t] = fmaf(xv, wek, aes[t]);
                aed[t] = fmaf(xv, wdk, aed[t]);
            }
        }
    }

    // ---- Phase B: fp32 shfl softmax (no max-shift: logits O(1), exact) ----
    {
        const int indeg = gb[1024 + v];
        const int mdin  = gb[1664];
        float den[8] = { 0.f,0.f,0.f,0.f,0.f,0.f,0.f,0.f };
        for (int e = 0; e < mdin; e++) {
            const int s = gb[v * MDI + e];
            const float valid = (e < indeg) ? 1.f : 0.f;
            #pragma unroll
            for (int t = 0; t < 8; t++) {
                float ev = __shfl(aes[t], s) + aed[t];
                ev = ev > 0.f ? ev : NSLOPE * ev;
                den[t] += valid * __expf(ev);
            }
        }
        float rden[8];
        #pragma unroll
        for (int t = 0; t < 8; t++) rden[t] = 1.f / den[t];

        const int odeg = gb[1600 + v];
        const int mdo  = gb[1665];
        float wb[8] = { 0.f,0.f,0.f,0.f,0.f,0.f,0.f,0.f };
        for (int j = 0; j < mdo; j++) {
            const int d = gb[1088 + v * MDO + j];
            const float valid = (j < odeg) ? 1.f : 0.f;
            #pragma unroll
            for (int t = 0; t < 8; t++) {
                float ev = aes[t] + __shfl(aed[t], d);
                ev = ev > 0.f ? ev : NSLOPE * ev;
                wb[t] += valid * __expf(ev) * __shfl(rden[t], d);
            }
        }
        #pragma unroll
        for (int t = 0; t < 8; t++) sm[L_WB + h * 544 + t * 68 + v] = wb[t];
    }
    __asm__ volatile("s_waitcnt lgkmcnt(0)" ::: "memory");   // wave-local drain

    // ---- Phase C: y[t,c] = sum_v wb[t,v]*xT[c,v], v-halved ----
    {
        const int vh = v >> 5, tp = (v >> 3) & 3, cg = v & 7;
        float ya[2][5] = { { 0.f,0.f,0.f,0.f,0.f }, { 0.f,0.f,0.f,0.f,0.f } };
        const float* xbase = &sm[L_XT + cg * 5 * 68 + vh * 32];
        const float* wb0   = &sm[L_WB + h * 544 + (2 * tp) * 68 + vh * 32];
        #pragma unroll
        for (int v4 = 0; v4 < 8; v4++) {
            const float4 wa = *(const float4*)(wb0 + v4 * 4);
            const float4 wbv = *(const float4*)(wb0 + 68 + v4 * 4);
            #pragma unroll
            for (int q = 0; q < 5; q++) {
                const float4 x4 = *(const float4*)(xbase + q * 68 + v4 * 4);
                ya[0][q] = fmaf(wa.x, x4.x, fmaf(wa.y, x4.y,
                           fmaf(wa.z, x4.z, fmaf(wa.w, x4.w, ya[0][q]))));
                ya[1][q] = fmaf(wbv.x, x4.x, fmaf(wbv.y, x4.y,
                           fmaf(wbv.z, x4.z, fmaf(wbv.w, x4.w, ya[1][q]))));
            }
        }
        #pragma unroll
        for (int i = 0; i < 2; i++)
            #pragma unroll
            for (int q = 0; q < 5; q++)
                ya[i][q] += __shfl_xor(ya[i][q], 32);
        if (vh == 0) {
            float* yr = &sm[L_Y + h * 328 + (2 * tp) * 41 + cg * 5];
            #pragma unroll
            for (int i = 0; i < 2; i++)
                #pragma unroll
                for (int q = 0; q < 5; q++)
                    yr[i * 41 + q] = ya[i][q];
        }
    }
    // wave-local: wave h reads only its own L_Y region; drain suffices.
    __asm__ volatile("s_waitcnt lgkmcnt(0)" ::: "memory");

    // ---- Phase D+E fused (wave-local): g -> bn2+elu -> pool8 via shfl ----
    {
        const int t = v >> 3, o = v & 7;
        const int f2d = h * 8 + o;
        float wfr[32];
        #pragma unroll
        for (int k = 0; k < 32; k++) wfr[k] = wfp[k * 32 + f2d];

        const float* yr = &sm[L_Y + h * 328 + t * 41];
        float acc = chlp[f2d] * yr[39];
        #pragma unroll
        for (int k = 0; k < 32; k++)
            acc = fmaf(wfr[k], yr[t + k], acc);

        // bn2 + elu on this (t, f2) element; then reduce over t (lane bits 5:3)
        const float a2 = a2c2[f2d], c2 = a2c2[32 + f2d];
        float y = fmaf(a2, acc * (1.f / 64.f), c2);
        y = y > 0.f ? y : __expf(y) - 1.f;
        y += __shfl_xor(y, 8);
        y += __shfl_xor(y, 16);
        y += __shfl_xor(y, 32);
        if (v < 8)
            pout[(b * T2c + tile) * 32 + h * 8 + v] = y * 0.125f;
    }
}

// ---------------------------------------------------------------------------
// conv3(K=16,'same') + bn3 + elu + avgpool(4): p[B,192,32] -> out[B,32,48].
// Weights read straight from global (k-contiguous float4; L2/L1-hot).
// ---------------------------------------------------------------------------
__global__ __launch_bounds__(TPB) void conv3_kernel(const float* __restrict__ pp,
                                                    const float* __restrict__ w3,
                                                    const float* __restrict__ g3,
                                                    const float* __restrict__ b3,
                                                    const float* __restrict__ m3,
                                                    const float* __restrict__ v3,
                                                    float* __restrict__ outp)
{
    __shared__ float pl[63 * 32];
    __shared__ float q[48 * 32];
    const int tid = threadIdx.x;
    const int b = blockIdx.x >> 2, cc = blockIdx.x & 3;

    for (int idx = tid; idx < 63 * 32; idx += TPB) {
        int r = idx >> 5, f2 = idx & 31;
        int tog = cc * 48 - 7 + r;
        pl[idx] = (tog >= 0 && tog < T2c) ? pp[(b * T2c + tog) * 32 + f2] : 0.f;
    }
    __syncthreads();

    const int f2o = tid & 31, grp = tid >> 5;
    const int tb = grp * 6;
    float acc[6] = { 0.f, 0.f, 0.f, 0.f, 0.f, 0.f };
    for (int f2i = 0; f2i < 32; f2i++) {
        float seg[21];
        #pragma unroll
        for (int r = 0; r < 21; r++) seg[r] = pl[(tb + r) * 32 + f2i];
        const float4* wrow = (const float4*)(w3 + (f2o * 32 + f2i) * 16);
        #pragma unroll
        for (int k4 = 0; k4 < 4; k4++) {
            const float4 w4 = wrow[k4];
            #pragma unroll
            for (int j = 0; j < 6; j++) {
                acc[j] = fmaf(seg[j + k4 * 4 + 0], w4.x,
                         fmaf(seg[j + k4 * 4 + 1], w4.y,
                         fmaf(seg[j + k4 * 4 + 2], w4.z,
                         fmaf(seg[j + k4 * 4 + 3], w4.w, acc[j]))));
            }
        }
    }
    const float a3 = g3[f2o] * rsqrtf(v3[f2o] + EPSc);
    const float c3 = b3[f2o] - a3 * m3[f2o];
    #pragma unroll
    for (int j = 0; j < 6; j++) {
        float y = fmaf(a3, acc[j], c3);
        y = y > 0.f ? y : __expf(y) - 1.f;
        q[(tb + j) * 32 + f2o] = y;
    }
    __syncthreads();
    for (int idx = tid; idx < 12 * 32; idx += TPB) {
        int t4 = idx >> 5, f2 = idx & 31;
        int r0 = t4 * 4;
        float s = q[r0 * 32 + f2] + q[(r0 + 1) * 32 + f2] +
                  q[(r0 + 2) * 32 + f2] + q[(r0 + 3) * 32 + f2];
        outp[(b * 32 + f2) * 48 + cc * 12 + t4] = s * 0.25f;
    }
}

// ---------------------------------------------------------------------------
extern "C" void kernel_launch(void* const* d_in, const int* in_sizes, int n_in,
                              void* d_out, int out_size, void* d_ws, size_t ws_size,
                              hipStream_t stream)
{
    const float* x    = (const float*)d_in[0];
    const float* c1w  = (const float*)d_in[1];
    const float* g1   = (const float*)d_in[2];
    const float* b1   = (const float*)d_in[3];
    const float* m1   = (const float*)d_in[4];
    const float* v1   = (const float*)d_in[5];
    const float* W    = (const float*)d_in[6];
    const float* asrc = (const float*)d_in[7];
    const float* adst = (const float*)d_in[8];
    const float* bias = (const float*)d_in[9];
    const float* g2   = (const float*)d_in[10];
    const float* b2   = (const float*)d_in[11];
    const float* m2   = (const float*)d_in[12];
    const float* v2   = (const float*)d_in[13];
    const float* w3   = (const float*)d_in[14];
    const float* g3   = (const float*)d_in[15];
    const float* b3   = (const float*)d_in[16];
    const float* m3   = (const float*)d_in[17];
    const float* v3   = (const float*)d_in[18];
    const int*   ei   = (const int*)d_in[19];
    const int    ne   = in_sizes[19] / 2;

    float* ws = (float*)d_ws;

    prep_kernel<<<1, TPB, 0, stream>>>(c1w, g1, b1, m1, v1, W, asrc, adst,
                                       bias, g2, b2, m2, v2, ei, ne, ws);

    gat_kernel<<<Bc * T2c, TPB, 0, stream>>>(x,
                                             ws + OW_WEFF, ws + OW_CHL,
                                             ws + OW_CES,
                                             ws + OW_WES, ws + OW_WED,
                                             ws + OW_A2C2,
                                             (const int*)(ws + OW_GRAPH),
                                             ws + OW_P);

    conv3_kernel<<<Bc * 4, TPB, 0, stream>>>(ws + OW_P, w3, g3, b3, m3, v3,
                                             (float*)d_out);
}